// Round 1
// baseline (1160.855 us; speedup 1.0000x reference)
//
#include <hip/hip_runtime.h>
#include <math.h>

// GAT (2 layers) on MI355X.
// Layer 1: Fin=128 -> H=4 heads x C=32 (concat -> 128), ReLU
// Layer 2: 128 -> H=1 x C=64
// Edges: E from input + N self loops. Softmax over incoming edges per dst.

#define NEG_SLOPE 0.2f

__device__ __forceinline__ float leaky(float v) { return v > 0.f ? v : NEG_SLOPE * v; }

__device__ __forceinline__ void atomicMaxF(float* addr, float val) {
  if (val >= 0.f) atomicMax((int*)addr, __float_as_int(val));
  else            atomicMin((unsigned int*)addr, __float_as_uint(val));
}

// ---------------- init ----------------
__global__ __launch_bounds__(256) void init_neginf_k(float* __restrict__ p, int n) {
  int i = blockIdx.x * 256 + threadIdx.x;
  if (i < n) p[i] = -INFINITY;
}

// ---------------- GEMM1: h1[N,128] = X[N,128] @ W[128,128] ----------------
__global__ __launch_bounds__(256) void gemm1_k(const float* __restrict__ X,
                                               const float* __restrict__ W,
                                               float* __restrict__ Hout, int N) {
  __shared__ float wl[128 * 128];      // 64 KB
  __shared__ float xl[32][132];        // ~16.5 KB, stride 132 keeps float4 align + banks spread
  for (int i = threadIdx.x; i < 128 * 32; i += 256)          // 128*128/4 float4s
    *(float4*)&wl[i * 4] = *(const float4*)&W[i * 4];
  int lane = threadIdx.x & 31, grp = threadIdx.x >> 5;       // 32 col-threads x 8 groups
  int c4 = lane * 4;
  for (int n0 = blockIdx.x * 32; n0 < N; n0 += gridDim.x * 32) {
    __syncthreads();
    for (int i = threadIdx.x; i < 32 * 32; i += 256) {       // stage 32 rows
      int r = i >> 5, cc = (i & 31) * 4;
      int n = n0 + r;
      float4 xv = make_float4(0.f, 0.f, 0.f, 0.f);
      if (n < N) xv = *(const float4*)&X[(size_t)n * 128 + cc];
      *(float4*)&xl[r][cc] = xv;
    }
    __syncthreads();
    float acc[4][4] = {};
    for (int k = 0; k < 128; ++k) {
      float4 w4 = *(const float4*)&wl[k * 128 + c4];
      #pragma unroll
      for (int j = 0; j < 4; ++j) {
        float xv = xl[grp * 4 + j][k];
        acc[j][0] += xv * w4.x; acc[j][1] += xv * w4.y;
        acc[j][2] += xv * w4.z; acc[j][3] += xv * w4.w;
      }
    }
    #pragma unroll
    for (int j = 0; j < 4; ++j) {
      int n = n0 + grp * 4 + j;
      if (n < N) *(float4*)&Hout[(size_t)n * 128 + c4] = make_float4(acc[j][0], acc[j][1], acc[j][2], acc[j][3]);
    }
  }
}

// ---------------- GEMM2: h2[N,64] = X[N,128] @ W[128,64] ----------------
__global__ __launch_bounds__(256) void gemm2_k(const float* __restrict__ X,
                                               const float* __restrict__ W,
                                               float* __restrict__ Hout, int N) {
  __shared__ float wl[128 * 64];       // 32 KB
  __shared__ float xl[64][132];        // ~33.8 KB
  for (int i = threadIdx.x; i < 128 * 16; i += 256)
    *(float4*)&wl[i * 4] = *(const float4*)&W[i * 4];
  int lane = threadIdx.x & 15, grp = threadIdx.x >> 4;       // 16 col-threads x 16 groups
  int c4 = lane * 4;
  for (int n0 = blockIdx.x * 64; n0 < N; n0 += gridDim.x * 64) {
    __syncthreads();
    for (int i = threadIdx.x; i < 64 * 32; i += 256) {       // stage 64 rows
      int r = i >> 5, cc = (i & 31) * 4;
      int n = n0 + r;
      float4 xv = make_float4(0.f, 0.f, 0.f, 0.f);
      if (n < N) xv = *(const float4*)&X[(size_t)n * 128 + cc];
      *(float4*)&xl[r][cc] = xv;
    }
    __syncthreads();
    float acc[4][4] = {};
    for (int k = 0; k < 128; ++k) {
      float4 w4 = *(const float4*)&wl[k * 64 + c4];
      #pragma unroll
      for (int j = 0; j < 4; ++j) {
        float xv = xl[grp * 4 + j][k];
        acc[j][0] += xv * w4.x; acc[j][1] += xv * w4.y;
        acc[j][2] += xv * w4.z; acc[j][3] += xv * w4.w;
      }
    }
    #pragma unroll
    for (int j = 0; j < 4; ++j) {
      int n = n0 + grp * 4 + j;
      if (n < N) *(float4*)&Hout[(size_t)n * 64 + c4] = make_float4(acc[j][0], acc[j][1], acc[j][2], acc[j][3]);
    }
  }
}

// ---------------- alpha projections ----------------
// layer1: per node, per head h (c=h*32+c'): as[n,h] = sum_c' h1[n,h,c']*a_src[h,c']
__global__ __launch_bounds__(128) void alpha1_k(const float* __restrict__ Hm,
                                                const float* __restrict__ aw_s,
                                                const float* __restrict__ aw_d,
                                                float* __restrict__ as, float* __restrict__ ad) {
  int n = blockIdx.x;
  int c = threadIdx.x;                 // 0..127
  float hv = Hm[(size_t)n * 128 + c];
  float ps = hv * aw_s[c];
  float pd = hv * aw_d[c];
  #pragma unroll
  for (int off = 16; off > 0; off >>= 1) {
    ps += __shfl_xor(ps, off);
    pd += __shfl_xor(pd, off);
  }
  if ((c & 31) == 0) {
    as[n * 4 + (c >> 5)] = ps;
    ad[n * 4 + (c >> 5)] = pd;
  }
}

// layer2: H=1, C=64
__global__ __launch_bounds__(64) void alpha2_k(const float* __restrict__ Hm,
                                               const float* __restrict__ aw_s,
                                               const float* __restrict__ aw_d,
                                               float* __restrict__ as, float* __restrict__ ad) {
  int n = blockIdx.x;
  int c = threadIdx.x;                 // 0..63
  float hv = Hm[(size_t)n * 64 + c];
  float ps = hv * aw_s[c];
  float pd = hv * aw_d[c];
  #pragma unroll
  for (int off = 32; off > 0; off >>= 1) {
    ps += __shfl_xor(ps, off);
    pd += __shfl_xor(pd, off);
  }
  if (c == 0) { as[n] = ps; ad[n] = pd; }
}

// ---------------- edge passes, layer 1 (H=4) ----------------
__global__ __launch_bounds__(256) void edge_max1_k(const int* __restrict__ ei, int E, int ET,
                                                   const float* __restrict__ as,
                                                   const float* __restrict__ ad,
                                                   float* __restrict__ m) {
  int e = blockIdx.x * 256 + threadIdx.x;
  if (e >= ET) return;
  int s, d;
  if (e < E) { s = ei[e]; d = ei[E + e]; } else { s = d = e - E; }
  float4 av = *(const float4*)&as[s * 4];
  float4 dv = *(const float4*)&ad[d * 4];
  atomicMaxF(&m[d * 4 + 0], leaky(av.x + dv.x));
  atomicMaxF(&m[d * 4 + 1], leaky(av.y + dv.y));
  atomicMaxF(&m[d * 4 + 2], leaky(av.z + dv.z));
  atomicMaxF(&m[d * 4 + 3], leaky(av.w + dv.w));
}

__global__ __launch_bounds__(256) void edge_den1_k(const int* __restrict__ ei, int E, int ET,
                                                   const float* __restrict__ as,
                                                   const float* __restrict__ ad,
                                                   const float* __restrict__ m,
                                                   float* __restrict__ den) {
  int e = blockIdx.x * 256 + threadIdx.x;
  if (e >= ET) return;
  int s, d;
  if (e < E) { s = ei[e]; d = ei[E + e]; } else { s = d = e - E; }
  float4 av = *(const float4*)&as[s * 4];
  float4 dv = *(const float4*)&ad[d * 4];
  float4 mv = *(const float4*)&m[d * 4];
  atomicAdd(&den[d * 4 + 0], __expf(leaky(av.x + dv.x) - mv.x));
  atomicAdd(&den[d * 4 + 1], __expf(leaky(av.y + dv.y) - mv.y));
  atomicAdd(&den[d * 4 + 2], __expf(leaky(av.z + dv.z) - mv.z));
  atomicAdd(&den[d * 4 + 3], __expf(leaky(av.w + dv.w) - mv.w));
}

// 2 edges per 256-thread block, 128 lanes per edge (one per channel)
__global__ __launch_bounds__(256) void edge_agg1_k(const int* __restrict__ ei, int E, int ET,
                                                   const float* __restrict__ as,
                                                   const float* __restrict__ ad,
                                                   const float* __restrict__ m,
                                                   const float* __restrict__ den,
                                                   const float* __restrict__ Hm,
                                                   float* __restrict__ out) {
  int eidx = blockIdx.x * 2 + (threadIdx.x >> 7);
  if (eidx >= ET) return;
  int c = threadIdx.x & 127;
  int s, d;
  if (eidx < E) { s = ei[eidx]; d = ei[E + eidx]; } else { s = d = eidx - E; }
  int h = c >> 5;
  float v = leaky(as[s * 4 + h] + ad[d * 4 + h]);
  float alpha = __expf(v - m[d * 4 + h]) / den[d * 4 + h];
  atomicAdd(&out[(size_t)d * 128 + c], Hm[(size_t)s * 128 + c] * alpha);
}

// ---------------- edge passes, layer 2 (H=1) ----------------
__global__ __launch_bounds__(256) void edge_max2_k(const int* __restrict__ ei, int E, int ET,
                                                   const float* __restrict__ as,
                                                   const float* __restrict__ ad,
                                                   float* __restrict__ m) {
  int e = blockIdx.x * 256 + threadIdx.x;
  if (e >= ET) return;
  int s, d;
  if (e < E) { s = ei[e]; d = ei[E + e]; } else { s = d = e - E; }
  atomicMaxF(&m[d], leaky(as[s] + ad[d]));
}

__global__ __launch_bounds__(256) void edge_den2_k(const int* __restrict__ ei, int E, int ET,
                                                   const float* __restrict__ as,
                                                   const float* __restrict__ ad,
                                                   const float* __restrict__ m,
                                                   float* __restrict__ den) {
  int e = blockIdx.x * 256 + threadIdx.x;
  if (e >= ET) return;
  int s, d;
  if (e < E) { s = ei[e]; d = ei[E + e]; } else { s = d = e - E; }
  atomicAdd(&den[d], __expf(leaky(as[s] + ad[d]) - m[d]));
}

// 4 edges per 256-thread block, 64 lanes per edge
__global__ __launch_bounds__(256) void edge_agg2_k(const int* __restrict__ ei, int E, int ET,
                                                   const float* __restrict__ as,
                                                   const float* __restrict__ ad,
                                                   const float* __restrict__ m,
                                                   const float* __restrict__ den,
                                                   const float* __restrict__ Hm,
                                                   float* __restrict__ out) {
  int eidx = blockIdx.x * 4 + (threadIdx.x >> 6);
  if (eidx >= ET) return;
  int c = threadIdx.x & 63;
  int s, d;
  if (eidx < E) { s = ei[eidx]; d = ei[E + eidx]; } else { s = d = eidx - E; }
  float v = leaky(as[s] + ad[d]);
  float alpha = __expf(v - m[d]) / den[d];
  atomicAdd(&out[(size_t)d * 64 + c], Hm[(size_t)s * 64 + c] * alpha);
}

// ---------------- epilogues ----------------
__global__ __launch_bounds__(256) void relu_bias1_k(float* __restrict__ p,
                                                    const float* __restrict__ b, size_t n) {
  size_t i = (size_t)blockIdx.x * 256 + threadIdx.x;
  if (i < n) p[i] = fmaxf(p[i] + b[i & 127], 0.f);
}

__global__ __launch_bounds__(256) void bias2_k(float* __restrict__ p,
                                               const float* __restrict__ b, size_t n) {
  size_t i = (size_t)blockIdx.x * 256 + threadIdx.x;
  if (i < n) p[i] += b[i & 63];
}

extern "C" void kernel_launch(void* const* d_in, const int* in_sizes, int n_in,
                              void* d_out, int out_size, void* d_ws, size_t ws_size,
                              hipStream_t stream) {
  const float* x   = (const float*)d_in[0];
  const int*   ei  = (const int*)d_in[1];
  // d_in[2] edge_weight: unused by GATConv (edge_dim unset)
  const float* W1  = (const float*)d_in[3];
  const float* aS1 = (const float*)d_in[4];
  const float* aD1 = (const float*)d_in[5];
  const float* b1  = (const float*)d_in[6];
  const float* W2  = (const float*)d_in[7];
  const float* aS2 = (const float*)d_in[8];
  const float* aD2 = (const float*)d_in[9];
  const float* b2  = (const float*)d_in[10];

  const int N  = in_sizes[0] / 128;
  const int E  = in_sizes[2];
  const int ET = E + N;

  float* ws   = (float*)d_ws;
  float* h1   = ws;                         // N*128
  float* out1 = h1   + (size_t)N * 128;     // N*128
  float* h2   = out1 + (size_t)N * 128;     // N*64
  float* as1  = h2   + (size_t)N * 64;      // 4N
  float* ad1  = as1  + (size_t)4 * N;       // 4N
  float* m1   = ad1  + (size_t)4 * N;       // 4N   (m1,m2 contiguous: one -inf init)
  float* m2   = m1   + (size_t)4 * N;       // N
  float* den1 = m2   + (size_t)N;           // 4N   (den1,den2 contiguous: one memset)
  float* den2 = den1 + (size_t)4 * N;       // N
  float* as2  = den2 + (size_t)N;           // N
  float* ad2  = as2  + (size_t)N;           // N
  float* out  = (float*)d_out;              // N*64

  // init accumulators (ws/out are poisoned 0xAA before every timed call)
  hipMemsetAsync(out1, 0, (size_t)N * 128 * sizeof(float), stream);
  hipMemsetAsync(den1, 0, (size_t)5 * N * sizeof(float), stream);
  hipMemsetAsync(d_out, 0, (size_t)N * 64 * sizeof(float), stream);
  init_neginf_k<<<(5 * N + 255) / 256, 256, 0, stream>>>(m1, 5 * N);

  const int eb  = (ET + 255) / 256;

  // ---- layer 1 ----
  gemm1_k<<<512, 256, 0, stream>>>(x, W1, h1, N);
  alpha1_k<<<N, 128, 0, stream>>>(h1, aS1, aD1, as1, ad1);
  edge_max1_k<<<eb, 256, 0, stream>>>(ei, E, ET, as1, ad1, m1);
  edge_den1_k<<<eb, 256, 0, stream>>>(ei, E, ET, as1, ad1, m1, den1);
  edge_agg1_k<<<(ET + 1) / 2, 256, 0, stream>>>(ei, E, ET, as1, ad1, m1, den1, h1, out1);
  relu_bias1_k<<<(int)(((size_t)N * 128 + 255) / 256), 256, 0, stream>>>(out1, b1, (size_t)N * 128);

  // ---- layer 2 ----
  gemm2_k<<<512, 256, 0, stream>>>(out1, W2, h2, N);
  alpha2_k<<<N, 64, 0, stream>>>(h2, aS2, aD2, as2, ad2);
  edge_max2_k<<<eb, 256, 0, stream>>>(ei, E, ET, as2, ad2, m2);
  edge_den2_k<<<eb, 256, 0, stream>>>(ei, E, ET, as2, ad2, m2, den2);
  edge_agg2_k<<<(ET + 3) / 4, 256, 0, stream>>>(ei, E, ET, as2, ad2, m2, den2, h2, out);
  bias2_k<<<(int)(((size_t)N * 64 + 255) / 256), 256, 0, stream>>>(out, b2, (size_t)N * 64);
}

// Round 2
// 540.731 us; speedup vs baseline: 2.1468x; 2.1468x over previous
//
#include <hip/hip_runtime.h>
#include <math.h>

// GAT (2 layers) on MI355X — CSR formulation.
// Layer 1: Fin=128 -> H=4 x C=32 (concat 128), +bias, ReLU  (fused in agg1)
// Layer 2: 128 -> H=1 x C=64, +bias                          (fused in agg2)
// CSR by dst built per call: hist -> 1-block scan -> scatter. Aggregation is
// one wave per dst node: online softmax over incoming edges, then sequential
// register-accumulated gather of h[src] rows. No float atomics anywhere.

#define NEG_SLOPE 0.2f

__device__ __forceinline__ float leaky(float v) { return v > 0.f ? v : NEG_SLOPE * v; }

// ---------------- CSR build ----------------
__global__ __launch_bounds__(256) void hist_k(const int* __restrict__ ei, int E, int ET,
                                              int* __restrict__ cnt) {
  int e = blockIdx.x * 256 + threadIdx.x;
  if (e >= ET) return;
  int d = (e < E) ? ei[E + e] : (e - E);
  atomicAdd(&cnt[d], 1);
}

__global__ __launch_bounds__(1024) void scan_k(const int* __restrict__ cnt,
                                               int* __restrict__ rowptr,
                                               int* __restrict__ cursor, int N) {
  __shared__ int part[1024];
  int t = threadIdx.x;
  int chunk = (N + 1023) >> 10;
  int lo = t * chunk, hi = min(lo + chunk, N);
  int s = 0;
  for (int i = lo; i < hi; ++i) s += cnt[i];
  part[t] = s;
  __syncthreads();
  for (int off = 1; off < 1024; off <<= 1) {
    int v = (t >= off) ? part[t - off] : 0;
    __syncthreads();
    part[t] += v;
    __syncthreads();
  }
  int run = (t == 0) ? 0 : part[t - 1];
  for (int i = lo; i < hi; ++i) {
    rowptr[i] = run; cursor[i] = run;
    run += cnt[i];
  }
  if (t == 1023) rowptr[N] = run;
}

__global__ __launch_bounds__(256) void scatter_k(const int* __restrict__ ei, int E, int ET,
                                                 int* __restrict__ cursor,
                                                 int* __restrict__ srcs) {
  int e = blockIdx.x * 256 + threadIdx.x;
  if (e >= ET) return;
  int s, d;
  if (e < E) { s = ei[e]; d = ei[E + e]; } else { s = d = e - E; }
  int pos = atomicAdd(&cursor[d], 1);
  srcs[pos] = s;
}

// ---------------- GEMM1: h1[N,128] = X[N,128] @ W[128,128] ----------------
__global__ __launch_bounds__(256) void gemm1_k(const float* __restrict__ X,
                                               const float* __restrict__ W,
                                               float* __restrict__ Hout, int N) {
  __shared__ float wl[128 * 128];
  __shared__ float xl[32][132];
  for (int i = threadIdx.x; i < 128 * 32; i += 256)
    *(float4*)&wl[i * 4] = *(const float4*)&W[i * 4];
  int lane = threadIdx.x & 31, grp = threadIdx.x >> 5;
  int c4 = lane * 4;
  for (int n0 = blockIdx.x * 32; n0 < N; n0 += gridDim.x * 32) {
    __syncthreads();
    for (int i = threadIdx.x; i < 32 * 32; i += 256) {
      int r = i >> 5, cc = (i & 31) * 4;
      int n = n0 + r;
      float4 xv = make_float4(0.f, 0.f, 0.f, 0.f);
      if (n < N) xv = *(const float4*)&X[(size_t)n * 128 + cc];
      *(float4*)&xl[r][cc] = xv;
    }
    __syncthreads();
    float acc[4][4] = {};
    for (int k = 0; k < 128; ++k) {
      float4 w4 = *(const float4*)&wl[k * 128 + c4];
      #pragma unroll
      for (int j = 0; j < 4; ++j) {
        float xv = xl[grp * 4 + j][k];
        acc[j][0] += xv * w4.x; acc[j][1] += xv * w4.y;
        acc[j][2] += xv * w4.z; acc[j][3] += xv * w4.w;
      }
    }
    #pragma unroll
    for (int j = 0; j < 4; ++j) {
      int n = n0 + grp * 4 + j;
      if (n < N) *(float4*)&Hout[(size_t)n * 128 + c4] = make_float4(acc[j][0], acc[j][1], acc[j][2], acc[j][3]);
    }
  }
}

// ---------------- GEMM2: h2[N,64] = X[N,128] @ W[128,64] ----------------
__global__ __launch_bounds__(256) void gemm2_k(const float* __restrict__ X,
                                               const float* __restrict__ W,
                                               float* __restrict__ Hout, int N) {
  __shared__ float wl[128 * 64];
  __shared__ float xl[64][132];
  for (int i = threadIdx.x; i < 128 * 16; i += 256)
    *(float4*)&wl[i * 4] = *(const float4*)&W[i * 4];
  int lane = threadIdx.x & 15, grp = threadIdx.x >> 4;
  int c4 = lane * 4;
  for (int n0 = blockIdx.x * 64; n0 < N; n0 += gridDim.x * 64) {
    __syncthreads();
    for (int i = threadIdx.x; i < 64 * 32; i += 256) {
      int r = i >> 5, cc = (i & 31) * 4;
      int n = n0 + r;
      float4 xv = make_float4(0.f, 0.f, 0.f, 0.f);
      if (n < N) xv = *(const float4*)&X[(size_t)n * 128 + cc];
      *(float4*)&xl[r][cc] = xv;
    }
    __syncthreads();
    float acc[4][4] = {};
    for (int k = 0; k < 128; ++k) {
      float4 w4 = *(const float4*)&wl[k * 64 + c4];
      #pragma unroll
      for (int j = 0; j < 4; ++j) {
        float xv = xl[grp * 4 + j][k];
        acc[j][0] += xv * w4.x; acc[j][1] += xv * w4.y;
        acc[j][2] += xv * w4.z; acc[j][3] += xv * w4.w;
      }
    }
    #pragma unroll
    for (int j = 0; j < 4; ++j) {
      int n = n0 + grp * 4 + j;
      if (n < N) *(float4*)&Hout[(size_t)n * 64 + c4] = make_float4(acc[j][0], acc[j][1], acc[j][2], acc[j][3]);
    }
  }
}

// ---------------- alpha projections ----------------
__global__ __launch_bounds__(128) void alpha1_k(const float* __restrict__ Hm,
                                                const float* __restrict__ aw_s,
                                                const float* __restrict__ aw_d,
                                                float* __restrict__ as, float* __restrict__ ad) {
  int n = blockIdx.x;
  int c = threadIdx.x;
  float hv = Hm[(size_t)n * 128 + c];
  float ps = hv * aw_s[c];
  float pd = hv * aw_d[c];
  #pragma unroll
  for (int off = 16; off > 0; off >>= 1) {
    ps += __shfl_xor(ps, off);
    pd += __shfl_xor(pd, off);
  }
  if ((c & 31) == 0) {
    as[n * 4 + (c >> 5)] = ps;
    ad[n * 4 + (c >> 5)] = pd;
  }
}

__global__ __launch_bounds__(64) void alpha2_k(const float* __restrict__ Hm,
                                               const float* __restrict__ aw_s,
                                               const float* __restrict__ aw_d,
                                               float* __restrict__ as, float* __restrict__ ad) {
  int n = blockIdx.x;
  int c = threadIdx.x;
  float hv = Hm[(size_t)n * 64 + c];
  float ps = hv * aw_s[c];
  float pd = hv * aw_d[c];
  #pragma unroll
  for (int off = 32; off > 0; off >>= 1) {
    ps += __shfl_xor(ps, off);
    pd += __shfl_xor(pd, off);
  }
  if (c == 0) { as[n] = ps; ad[n] = pd; }
}

// ---------------- layer-1 aggregation: wave per dst node ----------------
__global__ __launch_bounds__(256) void agg1_k(const int* __restrict__ rowptr,
                                              const int* __restrict__ srcs,
                                              const float* __restrict__ as,
                                              const float* __restrict__ ad,
                                              const float* __restrict__ Hm,
                                              const float* __restrict__ bias,
                                              float* __restrict__ out, int N) {
  int n = blockIdx.x * 4 + (threadIdx.x >> 6);
  if (n >= N) return;
  int lane = threadIdx.x & 63;
  int r0 = rowptr[n], r1 = rowptr[n + 1];
  float4 adn = *(const float4*)&ad[n * 4];

  // phase A: online softmax stats per head, per lane, then butterfly combine
  float mh[4] = {-INFINITY, -INFINITY, -INFINITY, -INFINITY};
  float sh[4] = {0.f, 0.f, 0.f, 0.f};
  for (int r = r0 + lane; r < r1; r += 64) {
    int s = srcs[r];
    float4 av = *(const float4*)&as[s * 4];
    float v[4] = { leaky(av.x + adn.x), leaky(av.y + adn.y),
                   leaky(av.z + adn.z), leaky(av.w + adn.w) };
    #pragma unroll
    for (int hh = 0; hh < 4; ++hh) {
      if (v[hh] > mh[hh]) { sh[hh] = sh[hh] * __expf(mh[hh] - v[hh]) + 1.f; mh[hh] = v[hh]; }
      else sh[hh] += __expf(v[hh] - mh[hh]);
    }
  }
  #pragma unroll
  for (int off = 1; off < 64; off <<= 1) {
    #pragma unroll
    for (int hh = 0; hh < 4; ++hh) {
      float mo = __shfl_xor(mh[hh], off);
      float so = __shfl_xor(sh[hh], off);
      float nm = fmaxf(mh[hh], mo);
      float f1 = (mh[hh] > -INFINITY) ? __expf(mh[hh] - nm) : 0.f;
      float f2 = (mo > -INFINITY) ? __expf(mo - nm) : 0.f;
      sh[hh] = sh[hh] * f1 + so * f2;
      mh[hh] = nm;
    }
  }

  int h = lane >> 4;   // head for channels {lane*2, lane*2+1}
  float mhh = (h == 0) ? mh[0] : (h == 1) ? mh[1] : (h == 2) ? mh[2] : mh[3];
  float inv = 1.f / ((h == 0) ? sh[0] : (h == 1) ? sh[1] : (h == 2) ? sh[2] : sh[3]);
  float adh = (h == 0) ? adn.x : (h == 1) ? adn.y : (h == 2) ? adn.z : adn.w;

  // phase B: gather h[src] rows, FMA with alpha, 2 channels per lane
  float accx = 0.f, accy = 0.f;
  int c2 = lane * 2;
  int r = r0;
  for (; r + 1 < r1; r += 2) {
    int sA = srcs[r], sB = srcs[r + 1];
    float aA = as[sA * 4 + h], aB = as[sB * 4 + h];
    float2 hA = *(const float2*)&Hm[(size_t)sA * 128 + c2];
    float2 hB = *(const float2*)&Hm[(size_t)sB * 128 + c2];
    float alA = __expf(leaky(aA + adh) - mhh) * inv;
    float alB = __expf(leaky(aB + adh) - mhh) * inv;
    accx += hA.x * alA + hB.x * alB;
    accy += hA.y * alA + hB.y * alB;
  }
  if (r < r1) {
    int sA = srcs[r];
    float aA = as[sA * 4 + h];
    float2 hA = *(const float2*)&Hm[(size_t)sA * 128 + c2];
    float alA = __expf(leaky(aA + adh) - mhh) * inv;
    accx += hA.x * alA;
    accy += hA.y * alA;
  }
  // fused bias + ReLU
  float2 o;
  o.x = fmaxf(accx + bias[c2], 0.f);
  o.y = fmaxf(accy + bias[c2 + 1], 0.f);
  *(float2*)&out[(size_t)n * 128 + c2] = o;
}

// ---------------- layer-2 aggregation: wave per dst node (H=1, C=64) ----------------
__global__ __launch_bounds__(256) void agg2_k(const int* __restrict__ rowptr,
                                              const int* __restrict__ srcs,
                                              const float* __restrict__ as,
                                              const float* __restrict__ ad,
                                              const float* __restrict__ Hm,
                                              const float* __restrict__ bias,
                                              float* __restrict__ out, int N) {
  int n = blockIdx.x * 4 + (threadIdx.x >> 6);
  if (n >= N) return;
  int lane = threadIdx.x & 63;
  int r0 = rowptr[n], r1 = rowptr[n + 1];
  float adn = ad[n];

  float mh = -INFINITY, sh = 0.f;
  for (int r = r0 + lane; r < r1; r += 64) {
    int s = srcs[r];
    float v = leaky(as[s] + adn);
    if (v > mh) { sh = sh * __expf(mh - v) + 1.f; mh = v; }
    else sh += __expf(v - mh);
  }
  #pragma unroll
  for (int off = 1; off < 64; off <<= 1) {
    float mo = __shfl_xor(mh, off);
    float so = __shfl_xor(sh, off);
    float nm = fmaxf(mh, mo);
    float f1 = (mh > -INFINITY) ? __expf(mh - nm) : 0.f;
    float f2 = (mo > -INFINITY) ? __expf(mo - nm) : 0.f;
    sh = sh * f1 + so * f2;
    mh = nm;
  }
  float inv = 1.f / sh;

  float acc = 0.f;
  int r = r0;
  for (; r + 1 < r1; r += 2) {
    int sA = srcs[r], sB = srcs[r + 1];
    float aA = as[sA], aB = as[sB];
    float hA = Hm[(size_t)sA * 64 + lane];
    float hB = Hm[(size_t)sB * 64 + lane];
    float alA = __expf(leaky(aA + adn) - mh) * inv;
    float alB = __expf(leaky(aB + adn) - mh) * inv;
    acc += hA * alA + hB * alB;
  }
  if (r < r1) {
    int sA = srcs[r];
    float hA = Hm[(size_t)sA * 64 + lane];
    float alA = __expf(leaky(as[sA] + adn) - mh) * inv;
    acc += hA * alA;
  }
  out[(size_t)n * 64 + lane] = acc + bias[lane];
}

extern "C" void kernel_launch(void* const* d_in, const int* in_sizes, int n_in,
                              void* d_out, int out_size, void* d_ws, size_t ws_size,
                              hipStream_t stream) {
  const float* x   = (const float*)d_in[0];
  const int*   ei  = (const int*)d_in[1];
  // d_in[2] edge_weight: unused by GATConv (edge_dim unset)
  const float* W1  = (const float*)d_in[3];
  const float* aS1 = (const float*)d_in[4];
  const float* aD1 = (const float*)d_in[5];
  const float* b1  = (const float*)d_in[6];
  const float* W2  = (const float*)d_in[7];
  const float* aS2 = (const float*)d_in[8];
  const float* aD2 = (const float*)d_in[9];
  const float* b2  = (const float*)d_in[10];

  const int N  = in_sizes[0] / 128;
  const int E  = in_sizes[2];
  const int ET = E + N;

  float* ws   = (float*)d_ws;
  float* h1   = ws;                           // N*128 (reused as h2 after layer 1)
  float* out1 = h1   + (size_t)N * 128;       // N*128
  float* as1  = out1 + (size_t)N * 128;       // 4N
  float* ad1  = as1  + (size_t)4 * N;         // 4N
  float* as2  = ad1  + (size_t)4 * N;         // N
  float* ad2  = as2  + (size_t)N;             // N
  int*   cnt    = (int*)(ad2 + (size_t)N);    // N
  int*   rowptr = cnt    + N;                 // N+1
  int*   cursor = rowptr + N + 1;             // N
  int*   srcs   = cursor + N;                 // ET
  float* h2   = h1;                           // alias (h1 dead after agg1)
  float* out  = (float*)d_out;                // N*64

  const int eb = (ET + 255) / 256;
  const int nb4 = (N + 3) / 4;

  // ---- CSR build (graph shared by both layers) ----
  hipMemsetAsync(cnt, 0, (size_t)N * sizeof(int), stream);
  hist_k<<<eb, 256, 0, stream>>>(ei, E, ET, cnt);
  scan_k<<<1, 1024, 0, stream>>>(cnt, rowptr, cursor, N);
  scatter_k<<<eb, 256, 0, stream>>>(ei, E, ET, cursor, srcs);

  // ---- layer 1 ----
  gemm1_k<<<512, 256, 0, stream>>>(x, W1, h1, N);
  alpha1_k<<<N, 128, 0, stream>>>(h1, aS1, aD1, as1, ad1);
  agg1_k<<<nb4, 256, 0, stream>>>(rowptr, srcs, as1, ad1, h1, b1, out1, N);

  // ---- layer 2 ----
  gemm2_k<<<512, 256, 0, stream>>>(out1, W2, h2, N);
  alpha2_k<<<N, 64, 0, stream>>>(h2, aS2, aD2, as2, ad2);
  agg2_k<<<nb4, 256, 0, stream>>>(rowptr, srcs, as2, ad2, h2, b2, out, N);
}

// Round 3
// 440.840 us; speedup vs baseline: 2.6333x; 1.2266x over previous
//
#include <hip/hip_runtime.h>
#include <math.h>

// GAT (2 layers) on MI355X — CSR formulation, multi-block scan.
// Layer 1: Fin=128 -> H=4 x C=32 (concat 128), +bias, ReLU  (fused in agg1)
// Layer 2: 128 -> H=1 x C=64, +bias                          (fused in agg2)
// CSR by dst built per call: hist -> 3-pass scan -> scatter. Aggregation is
// one wave per dst node: online softmax over incoming edges, then sequential
// register-accumulated gather of h[src] rows. No float atomics anywhere.

#define NEG_SLOPE 0.2f

__device__ __forceinline__ float leaky(float v) { return v > 0.f ? v : NEG_SLOPE * v; }

// ---------------- CSR build ----------------
__global__ __launch_bounds__(256) void hist_k(const int* __restrict__ ei, int E, int ET,
                                              int* __restrict__ cnt) {
  int e = blockIdx.x * 256 + threadIdx.x;
  if (e >= ET) return;
  int d = (e < E) ? ei[E + e] : (e - E);
  atomicAdd(&cnt[d], 1);
}

// pass 1: per-256-chunk exclusive scan + block totals
__global__ __launch_bounds__(256) void scan1_k(const int* __restrict__ cnt,
                                               int* __restrict__ rowtmp,
                                               int* __restrict__ bsum, int N) {
  int i = blockIdx.x * 256 + threadIdx.x;
  int v = (i < N) ? cnt[i] : 0;
  __shared__ int sm[256];
  sm[threadIdx.x] = v;
  __syncthreads();
  #pragma unroll
  for (int off = 1; off < 256; off <<= 1) {
    int t = (threadIdx.x >= off) ? sm[threadIdx.x - off] : 0;
    __syncthreads();
    sm[threadIdx.x] += t;
    __syncthreads();
  }
  if (i < N) rowtmp[i] = sm[threadIdx.x] - v;   // exclusive within block
  if (threadIdx.x == 255) bsum[blockIdx.x] = sm[255];
}

// pass 2: scan block totals (nb <= 256)
__global__ __launch_bounds__(256) void scan2_k(int* __restrict__ bsum, int nb) {
  __shared__ int sm[256];
  int v = (threadIdx.x < nb) ? bsum[threadIdx.x] : 0;
  sm[threadIdx.x] = v;
  __syncthreads();
  #pragma unroll
  for (int off = 1; off < 256; off <<= 1) {
    int t = (threadIdx.x >= off) ? sm[threadIdx.x - off] : 0;
    __syncthreads();
    sm[threadIdx.x] += t;
    __syncthreads();
  }
  if (threadIdx.x < nb) bsum[threadIdx.x] = sm[threadIdx.x] - v;  // exclusive
}

// pass 3: add block offsets, emit rowptr + cursor
__global__ __launch_bounds__(256) void scan3_k(const int* __restrict__ rowtmp,
                                               const int* __restrict__ bsum,
                                               int* __restrict__ rowptr,
                                               int* __restrict__ cursor, int N, int ET) {
  int i = blockIdx.x * 256 + threadIdx.x;
  if (i < N) {
    int v = rowtmp[i] + bsum[blockIdx.x];
    rowptr[i] = v;
    cursor[i] = v;
  }
  if (i == 0) rowptr[N] = ET;
}

__global__ __launch_bounds__(256) void scatter_k(const int* __restrict__ ei, int E, int ET,
                                                 int* __restrict__ cursor,
                                                 int* __restrict__ srcs) {
  int e = blockIdx.x * 256 + threadIdx.x;
  if (e >= ET) return;
  int s, d;
  if (e < E) { s = ei[e]; d = ei[E + e]; } else { s = d = e - E; }
  int pos = atomicAdd(&cursor[d], 1);
  srcs[pos] = s;
}

// ---------------- GEMM1: h1[N,128] = X[N,128] @ W[128,128] ----------------
__global__ __launch_bounds__(256) void gemm1_k(const float* __restrict__ X,
                                               const float* __restrict__ W,
                                               float* __restrict__ Hout, int N) {
  __shared__ float wl[128 * 128];
  __shared__ float xl[32][132];
  for (int i = threadIdx.x; i < 128 * 32; i += 256)
    *(float4*)&wl[i * 4] = *(const float4*)&W[i * 4];
  int lane = threadIdx.x & 31, grp = threadIdx.x >> 5;
  int c4 = lane * 4;
  for (int n0 = blockIdx.x * 32; n0 < N; n0 += gridDim.x * 32) {
    __syncthreads();
    for (int i = threadIdx.x; i < 32 * 32; i += 256) {
      int r = i >> 5, cc = (i & 31) * 4;
      int n = n0 + r;
      float4 xv = make_float4(0.f, 0.f, 0.f, 0.f);
      if (n < N) xv = *(const float4*)&X[(size_t)n * 128 + cc];
      *(float4*)&xl[r][cc] = xv;
    }
    __syncthreads();
    float acc[4][4] = {};
    for (int k = 0; k < 128; ++k) {
      float4 w4 = *(const float4*)&wl[k * 128 + c4];
      #pragma unroll
      for (int j = 0; j < 4; ++j) {
        float xv = xl[grp * 4 + j][k];
        acc[j][0] += xv * w4.x; acc[j][1] += xv * w4.y;
        acc[j][2] += xv * w4.z; acc[j][3] += xv * w4.w;
      }
    }
    #pragma unroll
    for (int j = 0; j < 4; ++j) {
      int n = n0 + grp * 4 + j;
      if (n < N) *(float4*)&Hout[(size_t)n * 128 + c4] = make_float4(acc[j][0], acc[j][1], acc[j][2], acc[j][3]);
    }
  }
}

// ---------------- GEMM2: h2[N,64] = X[N,128] @ W[128,64] ----------------
__global__ __launch_bounds__(256) void gemm2_k(const float* __restrict__ X,
                                               const float* __restrict__ W,
                                               float* __restrict__ Hout, int N) {
  __shared__ float wl[128 * 64];
  __shared__ float xl[64][132];
  for (int i = threadIdx.x; i < 128 * 16; i += 256)
    *(float4*)&wl[i * 4] = *(const float4*)&W[i * 4];
  int lane = threadIdx.x & 15, grp = threadIdx.x >> 4;
  int c4 = lane * 4;
  for (int n0 = blockIdx.x * 64; n0 < N; n0 += gridDim.x * 64) {
    __syncthreads();
    for (int i = threadIdx.x; i < 64 * 32; i += 256) {
      int r = i >> 5, cc = (i & 31) * 4;
      int n = n0 + r;
      float4 xv = make_float4(0.f, 0.f, 0.f, 0.f);
      if (n < N) xv = *(const float4*)&X[(size_t)n * 128 + cc];
      *(float4*)&xl[r][cc] = xv;
    }
    __syncthreads();
    float acc[4][4] = {};
    for (int k = 0; k < 128; ++k) {
      float4 w4 = *(const float4*)&wl[k * 64 + c4];
      #pragma unroll
      for (int j = 0; j < 4; ++j) {
        float xv = xl[grp * 4 + j][k];
        acc[j][0] += xv * w4.x; acc[j][1] += xv * w4.y;
        acc[j][2] += xv * w4.z; acc[j][3] += xv * w4.w;
      }
    }
    #pragma unroll
    for (int j = 0; j < 4; ++j) {
      int n = n0 + grp * 4 + j;
      if (n < N) *(float4*)&Hout[(size_t)n * 64 + c4] = make_float4(acc[j][0], acc[j][1], acc[j][2], acc[j][3]);
    }
  }
}

// ---------------- alpha projections ----------------
__global__ __launch_bounds__(128) void alpha1_k(const float* __restrict__ Hm,
                                                const float* __restrict__ aw_s,
                                                const float* __restrict__ aw_d,
                                                float* __restrict__ as, float* __restrict__ ad) {
  int n = blockIdx.x;
  int c = threadIdx.x;
  float hv = Hm[(size_t)n * 128 + c];
  float ps = hv * aw_s[c];
  float pd = hv * aw_d[c];
  #pragma unroll
  for (int off = 16; off > 0; off >>= 1) {
    ps += __shfl_xor(ps, off);
    pd += __shfl_xor(pd, off);
  }
  if ((c & 31) == 0) {
    as[n * 4 + (c >> 5)] = ps;
    ad[n * 4 + (c >> 5)] = pd;
  }
}

__global__ __launch_bounds__(64) void alpha2_k(const float* __restrict__ Hm,
                                               const float* __restrict__ aw_s,
                                               const float* __restrict__ aw_d,
                                               float* __restrict__ as, float* __restrict__ ad) {
  int n = blockIdx.x;
  int c = threadIdx.x;
  float hv = Hm[(size_t)n * 64 + c];
  float ps = hv * aw_s[c];
  float pd = hv * aw_d[c];
  #pragma unroll
  for (int off = 32; off > 0; off >>= 1) {
    ps += __shfl_xor(ps, off);
    pd += __shfl_xor(pd, off);
  }
  if (c == 0) { as[n] = ps; ad[n] = pd; }
}

// ---------------- layer-1 aggregation: wave per dst node ----------------
__global__ __launch_bounds__(256) void agg1_k(const int* __restrict__ rowptr,
                                              const int* __restrict__ srcs,
                                              const float* __restrict__ as,
                                              const float* __restrict__ ad,
                                              const float* __restrict__ Hm,
                                              const float* __restrict__ bias,
                                              float* __restrict__ out, int N) {
  int n = blockIdx.x * 4 + (threadIdx.x >> 6);
  if (n >= N) return;
  int lane = threadIdx.x & 63;
  int r0 = rowptr[n], r1 = rowptr[n + 1];
  float4 adn = *(const float4*)&ad[n * 4];

  // phase A: online softmax stats per head, per lane, then butterfly combine
  float mh[4] = {-INFINITY, -INFINITY, -INFINITY, -INFINITY};
  float sh[4] = {0.f, 0.f, 0.f, 0.f};
  for (int r = r0 + lane; r < r1; r += 64) {
    int s = srcs[r];
    float4 av = *(const float4*)&as[s * 4];
    float v[4] = { leaky(av.x + adn.x), leaky(av.y + adn.y),
                   leaky(av.z + adn.z), leaky(av.w + adn.w) };
    #pragma unroll
    for (int hh = 0; hh < 4; ++hh) {
      if (v[hh] > mh[hh]) { sh[hh] = sh[hh] * __expf(mh[hh] - v[hh]) + 1.f; mh[hh] = v[hh]; }
      else sh[hh] += __expf(v[hh] - mh[hh]);
    }
  }
  #pragma unroll
  for (int off = 1; off < 64; off <<= 1) {
    #pragma unroll
    for (int hh = 0; hh < 4; ++hh) {
      float mo = __shfl_xor(mh[hh], off);
      float so = __shfl_xor(sh[hh], off);
      float nm = fmaxf(mh[hh], mo);
      float f1 = (mh[hh] > -INFINITY) ? __expf(mh[hh] - nm) : 0.f;
      float f2 = (mo > -INFINITY) ? __expf(mo - nm) : 0.f;
      sh[hh] = sh[hh] * f1 + so * f2;
      mh[hh] = nm;
    }
  }

  int h = lane >> 4;   // head for channels {lane*2, lane*2+1}
  float mhh = (h == 0) ? mh[0] : (h == 1) ? mh[1] : (h == 2) ? mh[2] : mh[3];
  float inv = 1.f / ((h == 0) ? sh[0] : (h == 1) ? sh[1] : (h == 2) ? sh[2] : sh[3]);
  float adh = (h == 0) ? adn.x : (h == 1) ? adn.y : (h == 2) ? adn.z : adn.w;

  // phase B: gather h[src] rows, FMA with alpha, 2 channels per lane
  float accx = 0.f, accy = 0.f;
  int c2 = lane * 2;
  int r = r0;
  for (; r + 1 < r1; r += 2) {
    int sA = srcs[r], sB = srcs[r + 1];
    float aA = as[sA * 4 + h], aB = as[sB * 4 + h];
    float2 hA = *(const float2*)&Hm[(size_t)sA * 128 + c2];
    float2 hB = *(const float2*)&Hm[(size_t)sB * 128 + c2];
    float alA = __expf(leaky(aA + adh) - mhh) * inv;
    float alB = __expf(leaky(aB + adh) - mhh) * inv;
    accx += hA.x * alA + hB.x * alB;
    accy += hA.y * alA + hB.y * alB;
  }
  if (r < r1) {
    int sA = srcs[r];
    float aA = as[sA * 4 + h];
    float2 hA = *(const float2*)&Hm[(size_t)sA * 128 + c2];
    float alA = __expf(leaky(aA + adh) - mhh) * inv;
    accx += hA.x * alA;
    accy += hA.y * alA;
  }
  // fused bias + ReLU
  float2 o;
  o.x = fmaxf(accx + bias[c2], 0.f);
  o.y = fmaxf(accy + bias[c2 + 1], 0.f);
  *(float2*)&out[(size_t)n * 128 + c2] = o;
}

// ---------------- layer-2 aggregation: wave per dst node (H=1, C=64) ----------------
__global__ __launch_bounds__(256) void agg2_k(const int* __restrict__ rowptr,
                                              const int* __restrict__ srcs,
                                              const float* __restrict__ as,
                                              const float* __restrict__ ad,
                                              const float* __restrict__ Hm,
                                              const float* __restrict__ bias,
                                              float* __restrict__ out, int N) {
  int n = blockIdx.x * 4 + (threadIdx.x >> 6);
  if (n >= N) return;
  int lane = threadIdx.x & 63;
  int r0 = rowptr[n], r1 = rowptr[n + 1];
  float adn = ad[n];

  float mh = -INFINITY, sh = 0.f;
  for (int r = r0 + lane; r < r1; r += 64) {
    int s = srcs[r];
    float v = leaky(as[s] + adn);
    if (v > mh) { sh = sh * __expf(mh - v) + 1.f; mh = v; }
    else sh += __expf(v - mh);
  }
  #pragma unroll
  for (int off = 1; off < 64; off <<= 1) {
    float mo = __shfl_xor(mh, off);
    float so = __shfl_xor(sh, off);
    float nm = fmaxf(mh, mo);
    float f1 = (mh > -INFINITY) ? __expf(mh - nm) : 0.f;
    float f2 = (mo > -INFINITY) ? __expf(mo - nm) : 0.f;
    sh = sh * f1 + so * f2;
    mh = nm;
  }
  float inv = 1.f / sh;

  float acc = 0.f;
  int r = r0;
  for (; r + 1 < r1; r += 2) {
    int sA = srcs[r], sB = srcs[r + 1];
    float aA = as[sA], aB = as[sB];
    float hA = Hm[(size_t)sA * 64 + lane];
    float hB = Hm[(size_t)sB * 64 + lane];
    float alA = __expf(leaky(aA + adn) - mh) * inv;
    float alB = __expf(leaky(aB + adn) - mh) * inv;
    acc += hA * alA + hB * alB;
  }
  if (r < r1) {
    int sA = srcs[r];
    float hA = Hm[(size_t)sA * 64 + lane];
    float alA = __expf(leaky(as[sA] + adn) - mh) * inv;
    acc += hA * alA;
  }
  out[(size_t)n * 64 + lane] = acc + bias[lane];
}

extern "C" void kernel_launch(void* const* d_in, const int* in_sizes, int n_in,
                              void* d_out, int out_size, void* d_ws, size_t ws_size,
                              hipStream_t stream) {
  const float* x   = (const float*)d_in[0];
  const int*   ei  = (const int*)d_in[1];
  // d_in[2] edge_weight: unused by GATConv (edge_dim unset)
  const float* W1  = (const float*)d_in[3];
  const float* aS1 = (const float*)d_in[4];
  const float* aD1 = (const float*)d_in[5];
  const float* b1  = (const float*)d_in[6];
  const float* W2  = (const float*)d_in[7];
  const float* aS2 = (const float*)d_in[8];
  const float* aD2 = (const float*)d_in[9];
  const float* b2  = (const float*)d_in[10];

  const int N  = in_sizes[0] / 128;
  const int E  = in_sizes[2];
  const int ET = E + N;

  float* ws   = (float*)d_ws;
  float* h1   = ws;                           // N*128 (reused as h2 after layer 1)
  float* out1 = h1   + (size_t)N * 128;       // N*128
  float* as1  = out1 + (size_t)N * 128;       // 4N
  float* ad1  = as1  + (size_t)4 * N;         // 4N
  float* as2  = ad1  + (size_t)4 * N;         // N
  float* ad2  = as2  + (size_t)N;             // N
  int*   cnt    = (int*)(ad2 + (size_t)N);    // N
  int*   rowptr = cnt    + N;                 // N+1
  int*   cursor = rowptr + N + 1;             // N
  int*   rowtmp = cursor + N;                 // N
  int*   bsum   = rowtmp + N;                 // 256
  int*   srcs   = bsum   + 256;               // ET
  float* h2   = h1;                           // alias (h1 dead after agg1)
  float* out  = (float*)d_out;                // N*64

  const int eb  = (ET + 255) / 256;
  const int nb  = (N + 255) / 256;            // 196 scan blocks (nb <= 256 required)
  const int nb4 = (N + 3) / 4;

  // ---- CSR build (graph shared by both layers) ----
  hipMemsetAsync(cnt, 0, (size_t)N * sizeof(int), stream);
  hist_k<<<eb, 256, 0, stream>>>(ei, E, ET, cnt);
  scan1_k<<<nb, 256, 0, stream>>>(cnt, rowtmp, bsum, N);
  scan2_k<<<1, 256, 0, stream>>>(bsum, nb);
  scan3_k<<<nb, 256, 0, stream>>>(rowtmp, bsum, rowptr, cursor, N, ET);
  scatter_k<<<eb, 256, 0, stream>>>(ei, E, ET, cursor, srcs);

  // ---- layer 1 ----
  gemm1_k<<<512, 256, 0, stream>>>(x, W1, h1, N);
  alpha1_k<<<N, 128, 0, stream>>>(h1, aS1, aD1, as1, ad1);
  agg1_k<<<nb4, 256, 0, stream>>>(rowptr, srcs, as1, ad1, h1, b1, out1, N);

  // ---- layer 2 ----
  gemm2_k<<<512, 256, 0, stream>>>(out1, W2, h2, N);
  alpha2_k<<<N, 64, 0, stream>>>(h2, aS2, aD2, as2, ad2);
  agg2_k<<<nb4, 256, 0, stream>>>(rowptr, srcs, as2, ad2, h2, b2, out, N);
}

// Round 4
// 395.877 us; speedup vs baseline: 2.9324x; 1.1136x over previous
//
#include <hip/hip_runtime.h>
#include <math.h>

// GAT (2 layers) on MI355X — CSR formulation, multi-block scan, 4-way
// edge-parallel gather in aggregation.
// Layer 1: Fin=128 -> H=4 x C=32 (concat 128), +bias, ReLU  (fused in agg1)
// Layer 2: 128 -> H=1 x C=64, +bias                          (fused in agg2)
// Aggregation: one wave per dst node. Softmax stats via max-butterfly then
// exp-sum-butterfly. Gather phase: 4 edge-groups x 16 lanes, each group pulls
// a different src row (4 independent memory streams), cross-group shfl reduce.

#define NEG_SLOPE 0.2f

__device__ __forceinline__ float leaky(float v) { return v > 0.f ? v : NEG_SLOPE * v; }

// ---------------- CSR build ----------------
__global__ __launch_bounds__(256) void hist_k(const int* __restrict__ ei, int E, int ET,
                                              int* __restrict__ cnt) {
  int e = blockIdx.x * 256 + threadIdx.x;
  if (e >= ET) return;
  int d = (e < E) ? ei[E + e] : (e - E);
  atomicAdd(&cnt[d], 1);
}

__global__ __launch_bounds__(256) void scan1_k(const int* __restrict__ cnt,
                                               int* __restrict__ rowtmp,
                                               int* __restrict__ bsum, int N) {
  int i = blockIdx.x * 256 + threadIdx.x;
  int v = (i < N) ? cnt[i] : 0;
  __shared__ int sm[256];
  sm[threadIdx.x] = v;
  __syncthreads();
  #pragma unroll
  for (int off = 1; off < 256; off <<= 1) {
    int t = (threadIdx.x >= off) ? sm[threadIdx.x - off] : 0;
    __syncthreads();
    sm[threadIdx.x] += t;
    __syncthreads();
  }
  if (i < N) rowtmp[i] = sm[threadIdx.x] - v;
  if (threadIdx.x == 255) bsum[blockIdx.x] = sm[255];
}

__global__ __launch_bounds__(256) void scan2_k(int* __restrict__ bsum, int nb) {
  __shared__ int sm[256];
  int v = (threadIdx.x < nb) ? bsum[threadIdx.x] : 0;
  sm[threadIdx.x] = v;
  __syncthreads();
  #pragma unroll
  for (int off = 1; off < 256; off <<= 1) {
    int t = (threadIdx.x >= off) ? sm[threadIdx.x - off] : 0;
    __syncthreads();
    sm[threadIdx.x] += t;
    __syncthreads();
  }
  if (threadIdx.x < nb) bsum[threadIdx.x] = sm[threadIdx.x] - v;
}

__global__ __launch_bounds__(256) void scan3_k(const int* __restrict__ rowtmp,
                                               const int* __restrict__ bsum,
                                               int* __restrict__ rowptr,
                                               int* __restrict__ cursor, int N, int ET) {
  int i = blockIdx.x * 256 + threadIdx.x;
  if (i < N) {
    int v = rowtmp[i] + bsum[blockIdx.x];
    rowptr[i] = v;
    cursor[i] = v;
  }
  if (i == 0) rowptr[N] = ET;
}

__global__ __launch_bounds__(256) void scatter_k(const int* __restrict__ ei, int E, int ET,
                                                 int* __restrict__ cursor,
                                                 int* __restrict__ srcs) {
  int e = blockIdx.x * 256 + threadIdx.x;
  if (e >= ET) return;
  int s, d;
  if (e < E) { s = ei[e]; d = ei[E + e]; } else { s = d = e - E; }
  int pos = atomicAdd(&cursor[d], 1);
  srcs[pos] = s;
}

// ---------------- GEMM1: h1[N,128] = X[N,128] @ W[128,128] ----------------
__global__ __launch_bounds__(256) void gemm1_k(const float* __restrict__ X,
                                               const float* __restrict__ W,
                                               float* __restrict__ Hout, int N) {
  __shared__ float wl[128 * 128];
  __shared__ float xl[32][132];
  for (int i = threadIdx.x; i < 128 * 32; i += 256)
    *(float4*)&wl[i * 4] = *(const float4*)&W[i * 4];
  int lane = threadIdx.x & 31, grp = threadIdx.x >> 5;
  int c4 = lane * 4;
  for (int n0 = blockIdx.x * 32; n0 < N; n0 += gridDim.x * 32) {
    __syncthreads();
    for (int i = threadIdx.x; i < 32 * 32; i += 256) {
      int r = i >> 5, cc = (i & 31) * 4;
      int n = n0 + r;
      float4 xv = make_float4(0.f, 0.f, 0.f, 0.f);
      if (n < N) xv = *(const float4*)&X[(size_t)n * 128 + cc];
      *(float4*)&xl[r][cc] = xv;
    }
    __syncthreads();
    float acc[4][4] = {};
    for (int k = 0; k < 128; ++k) {
      float4 w4 = *(const float4*)&wl[k * 128 + c4];
      #pragma unroll
      for (int j = 0; j < 4; ++j) {
        float xv = xl[grp * 4 + j][k];
        acc[j][0] += xv * w4.x; acc[j][1] += xv * w4.y;
        acc[j][2] += xv * w4.z; acc[j][3] += xv * w4.w;
      }
    }
    #pragma unroll
    for (int j = 0; j < 4; ++j) {
      int n = n0 + grp * 4 + j;
      if (n < N) *(float4*)&Hout[(size_t)n * 128 + c4] = make_float4(acc[j][0], acc[j][1], acc[j][2], acc[j][3]);
    }
  }
}

// ---------------- GEMM2: h2[N,64] = X[N,128] @ W[128,64] ----------------
__global__ __launch_bounds__(256) void gemm2_k(const float* __restrict__ X,
                                               const float* __restrict__ W,
                                               float* __restrict__ Hout, int N) {
  __shared__ float wl[128 * 64];
  __shared__ float xl[64][132];
  for (int i = threadIdx.x; i < 128 * 16; i += 256)
    *(float4*)&wl[i * 4] = *(const float4*)&W[i * 4];
  int lane = threadIdx.x & 15, grp = threadIdx.x >> 4;
  int c4 = lane * 4;
  for (int n0 = blockIdx.x * 64; n0 < N; n0 += gridDim.x * 64) {
    __syncthreads();
    for (int i = threadIdx.x; i < 64 * 32; i += 256) {
      int r = i >> 5, cc = (i & 31) * 4;
      int n = n0 + r;
      float4 xv = make_float4(0.f, 0.f, 0.f, 0.f);
      if (n < N) xv = *(const float4*)&X[(size_t)n * 128 + cc];
      *(float4*)&xl[r][cc] = xv;
    }
    __syncthreads();
    float acc[4][4] = {};
    for (int k = 0; k < 128; ++k) {
      float4 w4 = *(const float4*)&wl[k * 64 + c4];
      #pragma unroll
      for (int j = 0; j < 4; ++j) {
        float xv = xl[grp * 4 + j][k];
        acc[j][0] += xv * w4.x; acc[j][1] += xv * w4.y;
        acc[j][2] += xv * w4.z; acc[j][3] += xv * w4.w;
      }
    }
    #pragma unroll
    for (int j = 0; j < 4; ++j) {
      int n = n0 + grp * 4 + j;
      if (n < N) *(float4*)&Hout[(size_t)n * 64 + c4] = make_float4(acc[j][0], acc[j][1], acc[j][2], acc[j][3]);
    }
  }
}

// ---------------- alpha projections ----------------
__global__ __launch_bounds__(128) void alpha1_k(const float* __restrict__ Hm,
                                                const float* __restrict__ aw_s,
                                                const float* __restrict__ aw_d,
                                                float* __restrict__ as, float* __restrict__ ad) {
  int n = blockIdx.x;
  int c = threadIdx.x;
  float hv = Hm[(size_t)n * 128 + c];
  float ps = hv * aw_s[c];
  float pd = hv * aw_d[c];
  #pragma unroll
  for (int off = 16; off > 0; off >>= 1) {
    ps += __shfl_xor(ps, off);
    pd += __shfl_xor(pd, off);
  }
  if ((c & 31) == 0) {
    as[n * 4 + (c >> 5)] = ps;
    ad[n * 4 + (c >> 5)] = pd;
  }
}

__global__ __launch_bounds__(64) void alpha2_k(const float* __restrict__ Hm,
                                               const float* __restrict__ aw_s,
                                               const float* __restrict__ aw_d,
                                               float* __restrict__ as, float* __restrict__ ad) {
  int n = blockIdx.x;
  int c = threadIdx.x;
  float hv = Hm[(size_t)n * 64 + c];
  float ps = hv * aw_s[c];
  float pd = hv * aw_d[c];
  #pragma unroll
  for (int off = 32; off > 0; off >>= 1) {
    ps += __shfl_xor(ps, off);
    pd += __shfl_xor(pd, off);
  }
  if (c == 0) { as[n] = ps; ad[n] = pd; }
}

// ---------------- layer-1 aggregation: wave per dst node ----------------
// lanes = 4 edge-groups (grp) x 16 channel-lanes (gl). lane gl covers
// channels gl*8..gl*8+7 (all within head gl>>2 since 8 | 32).
__global__ __launch_bounds__(256) void agg1_k(const int* __restrict__ rowptr,
                                              const int* __restrict__ srcs,
                                              const float* __restrict__ as,
                                              const float* __restrict__ ad,
                                              const float* __restrict__ Hm,
                                              const float* __restrict__ bias,
                                              float* __restrict__ out, int N) {
  int n = blockIdx.x * 4 + (threadIdx.x >> 6);
  if (n >= N) return;
  int lane = threadIdx.x & 63;
  int grp = lane >> 4;
  int gl  = lane & 15;
  int r0 = rowptr[n], r1 = rowptr[n + 1];
  float4 adn = *(const float4*)&ad[n * 4];

  // phase A1: per-head max over edges (lane-strided), butterfly
  float m0 = -INFINITY, m1 = -INFINITY, m2 = -INFINITY, m3 = -INFINITY;
  for (int r = r0 + lane; r < r1; r += 64) {
    int s = srcs[r];
    float4 av = *(const float4*)&as[s * 4];
    m0 = fmaxf(m0, leaky(av.x + adn.x));
    m1 = fmaxf(m1, leaky(av.y + adn.y));
    m2 = fmaxf(m2, leaky(av.z + adn.z));
    m3 = fmaxf(m3, leaky(av.w + adn.w));
  }
  #pragma unroll
  for (int off = 32; off > 0; off >>= 1) {
    m0 = fmaxf(m0, __shfl_xor(m0, off));
    m1 = fmaxf(m1, __shfl_xor(m1, off));
    m2 = fmaxf(m2, __shfl_xor(m2, off));
    m3 = fmaxf(m3, __shfl_xor(m3, off));
  }
  // phase A2: sum of exp (srcs/as now L1-hot), butterfly
  float s0 = 0.f, s1 = 0.f, s2 = 0.f, s3 = 0.f;
  for (int r = r0 + lane; r < r1; r += 64) {
    int s = srcs[r];
    float4 av = *(const float4*)&as[s * 4];
    s0 += __expf(leaky(av.x + adn.x) - m0);
    s1 += __expf(leaky(av.y + adn.y) - m1);
    s2 += __expf(leaky(av.z + adn.z) - m2);
    s3 += __expf(leaky(av.w + adn.w) - m3);
  }
  #pragma unroll
  for (int off = 32; off > 0; off >>= 1) {
    s0 += __shfl_xor(s0, off); s1 += __shfl_xor(s1, off);
    s2 += __shfl_xor(s2, off); s3 += __shfl_xor(s3, off);
  }

  int h = gl >> 2;
  float mhh = (h == 0) ? m0 : (h == 1) ? m1 : (h == 2) ? m2 : m3;
  float inv = 1.f / ((h == 0) ? s0 : (h == 1) ? s1 : (h == 2) ? s2 : s3);
  float adh = (h == 0) ? adn.x : (h == 1) ? adn.y : (h == 2) ? adn.z : adn.w;

  // phase B: 4 edges in flight, each lane 8 channels
  float a0 = 0.f, a1 = 0.f, a2 = 0.f, a3 = 0.f,
        a4 = 0.f, a5 = 0.f, a6 = 0.f, a7 = 0.f;
  int cbase = gl * 8;
  for (int r = r0; r < r1; r += 4) {
    int rr = r + grp;
    bool valid = rr < r1;
    int s = srcs[valid ? rr : (r1 - 1)];
    float av = as[s * 4 + h];
    float al = valid ? (__expf(leaky(av + adh) - mhh) * inv) : 0.f;
    const float* row = &Hm[(size_t)s * 128 + cbase];
    float4 ha = *(const float4*)row;
    float4 hb = *(const float4*)(row + 4);
    a0 += ha.x * al; a1 += ha.y * al; a2 += ha.z * al; a3 += ha.w * al;
    a4 += hb.x * al; a5 += hb.y * al; a6 += hb.z * al; a7 += hb.w * al;
  }
  // cross-group reduce (groups differ in bits 4,5 of lane)
  a0 += __shfl_xor(a0, 16); a0 += __shfl_xor(a0, 32);
  a1 += __shfl_xor(a1, 16); a1 += __shfl_xor(a1, 32);
  a2 += __shfl_xor(a2, 16); a2 += __shfl_xor(a2, 32);
  a3 += __shfl_xor(a3, 16); a3 += __shfl_xor(a3, 32);
  a4 += __shfl_xor(a4, 16); a4 += __shfl_xor(a4, 32);
  a5 += __shfl_xor(a5, 16); a5 += __shfl_xor(a5, 32);
  a6 += __shfl_xor(a6, 16); a6 += __shfl_xor(a6, 32);
  a7 += __shfl_xor(a7, 16); a7 += __shfl_xor(a7, 32);

  if (grp == 0) {
    float4 b0 = *(const float4*)&bias[cbase];
    float4 b1 = *(const float4*)&bias[cbase + 4];
    float4 o0, o1;
    o0.x = fmaxf(a0 + b0.x, 0.f); o0.y = fmaxf(a1 + b0.y, 0.f);
    o0.z = fmaxf(a2 + b0.z, 0.f); o0.w = fmaxf(a3 + b0.w, 0.f);
    o1.x = fmaxf(a4 + b1.x, 0.f); o1.y = fmaxf(a5 + b1.y, 0.f);
    o1.z = fmaxf(a6 + b1.z, 0.f); o1.w = fmaxf(a7 + b1.w, 0.f);
    *(float4*)&out[(size_t)n * 128 + cbase] = o0;
    *(float4*)&out[(size_t)n * 128 + cbase + 4] = o1;
  }
}

// ---------------- layer-2 aggregation: wave per dst node (H=1, C=64) ----------------
__global__ __launch_bounds__(256) void agg2_k(const int* __restrict__ rowptr,
                                              const int* __restrict__ srcs,
                                              const float* __restrict__ as,
                                              const float* __restrict__ ad,
                                              const float* __restrict__ Hm,
                                              const float* __restrict__ bias,
                                              float* __restrict__ out, int N) {
  int n = blockIdx.x * 4 + (threadIdx.x >> 6);
  if (n >= N) return;
  int lane = threadIdx.x & 63;
  int grp = lane >> 4;
  int gl  = lane & 15;
  int r0 = rowptr[n], r1 = rowptr[n + 1];
  float adn = ad[n];

  float mh = -INFINITY;
  for (int r = r0 + lane; r < r1; r += 64)
    mh = fmaxf(mh, leaky(as[srcs[r]] + adn));
  #pragma unroll
  for (int off = 32; off > 0; off >>= 1)
    mh = fmaxf(mh, __shfl_xor(mh, off));

  float sh = 0.f;
  for (int r = r0 + lane; r < r1; r += 64)
    sh += __expf(leaky(as[srcs[r]] + adn) - mh);
  #pragma unroll
  for (int off = 32; off > 0; off >>= 1)
    sh += __shfl_xor(sh, off);
  float inv = 1.f / sh;

  float a0 = 0.f, a1 = 0.f, a2 = 0.f, a3 = 0.f;
  int cbase = gl * 4;
  for (int r = r0; r < r1; r += 4) {
    int rr = r + grp;
    bool valid = rr < r1;
    int s = srcs[valid ? rr : (r1 - 1)];
    float al = valid ? (__expf(leaky(as[s] + adn) - mh) * inv) : 0.f;
    float4 hv = *(const float4*)&Hm[(size_t)s * 64 + cbase];
    a0 += hv.x * al; a1 += hv.y * al; a2 += hv.z * al; a3 += hv.w * al;
  }
  a0 += __shfl_xor(a0, 16); a0 += __shfl_xor(a0, 32);
  a1 += __shfl_xor(a1, 16); a1 += __shfl_xor(a1, 32);
  a2 += __shfl_xor(a2, 16); a2 += __shfl_xor(a2, 32);
  a3 += __shfl_xor(a3, 16); a3 += __shfl_xor(a3, 32);

  if (grp == 0) {
    float4 bv = *(const float4*)&bias[cbase];
    float4 o;
    o.x = a0 + bv.x; o.y = a1 + bv.y; o.z = a2 + bv.z; o.w = a3 + bv.w;
    *(float4*)&out[(size_t)n * 64 + cbase] = o;
  }
}

extern "C" void kernel_launch(void* const* d_in, const int* in_sizes, int n_in,
                              void* d_out, int out_size, void* d_ws, size_t ws_size,
                              hipStream_t stream) {
  const float* x   = (const float*)d_in[0];
  const int*   ei  = (const int*)d_in[1];
  // d_in[2] edge_weight: unused by GATConv (edge_dim unset)
  const float* W1  = (const float*)d_in[3];
  const float* aS1 = (const float*)d_in[4];
  const float* aD1 = (const float*)d_in[5];
  const float* b1  = (const float*)d_in[6];
  const float* W2  = (const float*)d_in[7];
  const float* aS2 = (const float*)d_in[8];
  const float* aD2 = (const float*)d_in[9];
  const float* b2  = (const float*)d_in[10];

  const int N  = in_sizes[0] / 128;
  const int E  = in_sizes[2];
  const int ET = E + N;

  float* ws   = (float*)d_ws;
  float* h1   = ws;                           // N*128 (reused as h2 after layer 1)
  float* out1 = h1   + (size_t)N * 128;       // N*128
  float* as1  = out1 + (size_t)N * 128;       // 4N
  float* ad1  = as1  + (size_t)4 * N;         // 4N
  float* as2  = ad1  + (size_t)4 * N;         // N
  float* ad2  = as2  + (size_t)N;             // N
  int*   cnt    = (int*)(ad2 + (size_t)N);    // N
  int*   rowptr = cnt    + N;                 // N+1
  int*   cursor = rowptr + N + 1;             // N
  int*   rowtmp = cursor + N;                 // N
  int*   bsum   = rowtmp + N;                 // 256
  int*   srcs   = bsum   + 256;               // ET
  float* h2   = h1;                           // alias (h1 dead after agg1)
  float* out  = (float*)d_out;                // N*64

  const int eb  = (ET + 255) / 256;
  const int nb  = (N + 255) / 256;            // scan blocks (nb <= 256 required)
  const int nb4 = (N + 3) / 4;

  // ---- CSR build (graph shared by both layers) ----
  hipMemsetAsync(cnt, 0, (size_t)N * sizeof(int), stream);
  hist_k<<<eb, 256, 0, stream>>>(ei, E, ET, cnt);
  scan1_k<<<nb, 256, 0, stream>>>(cnt, rowtmp, bsum, N);
  scan2_k<<<1, 256, 0, stream>>>(bsum, nb);
  scan3_k<<<nb, 256, 0, stream>>>(rowtmp, bsum, rowptr, cursor, N, ET);
  scatter_k<<<eb, 256, 0, stream>>>(ei, E, ET, cursor, srcs);

  // ---- layer 1 ----
  gemm1_k<<<512, 256, 0, stream>>>(x, W1, h1, N);
  alpha1_k<<<N, 128, 0, stream>>>(h1, aS1, aD1, as1, ad1);
  agg1_k<<<nb4, 256, 0, stream>>>(rowptr, srcs, as1, ad1, h1, b1, out1, N);

  // ---- layer 2 ----
  gemm2_k<<<512, 256, 0, stream>>>(out1, W2, h2, N);
  alpha2_k<<<N, 64, 0, stream>>>(h2, aS2, aD2, as2, ad2);
  agg2_k<<<nb4, 256, 0, stream>>>(rowptr, srcs, as2, ad2, h2, b2, out, N);
}

// Round 6
// 344.034 us; speedup vs baseline: 3.3742x; 1.1507x over previous
//
#include <hip/hip_runtime.h>
#include <math.h>

// GAT (2 layers) on MI355X — CSR + fused-alpha GEMMs + shfl-alpha aggregation.
// Layer 1: Fin=128 -> H=4 x C=32 (concat 128), +bias, ReLU  (fused in agg1)
// Layer 2: 128 -> H=1 x C=64, +bias                          (fused in agg2)
// agg: wave per dst node. deg<=64: one edge per lane, single-pass softmax,
// per-lane alpha broadcast to gather groups via shfl. CRITICAL: all __shfl
// calls execute at FULL exec mask (wave-uniform loop bounds, masked validity)
// — divergent-loop shfl from inactive lanes is undefined on CDNA.

#define NEG_SLOPE 0.2f

__device__ __forceinline__ float leaky(float v) { return v > 0.f ? v : NEG_SLOPE * v; }

// ---------------- CSR build ----------------
__global__ __launch_bounds__(256) void hist_k(const int* __restrict__ ei, int E, int ET,
                                              int* __restrict__ cnt) {
  int e = blockIdx.x * 256 + threadIdx.x;
  if (e >= ET) return;
  int d = (e < E) ? ei[E + e] : (e - E);
  atomicAdd(&cnt[d], 1);
}

__global__ __launch_bounds__(256) void scan1_k(const int* __restrict__ cnt,
                                               int* __restrict__ rowtmp,
                                               int* __restrict__ bsum, int N) {
  int i = blockIdx.x * 256 + threadIdx.x;
  int v = (i < N) ? cnt[i] : 0;
  __shared__ int sm[256];
  sm[threadIdx.x] = v;
  __syncthreads();
  #pragma unroll
  for (int off = 1; off < 256; off <<= 1) {
    int t = (threadIdx.x >= off) ? sm[threadIdx.x - off] : 0;
    __syncthreads();
    sm[threadIdx.x] += t;
    __syncthreads();
  }
  if (i < N) rowtmp[i] = sm[threadIdx.x] - v;
  if (threadIdx.x == 255) bsum[blockIdx.x] = sm[255];
}

__global__ __launch_bounds__(256) void scan2_k(int* __restrict__ bsum, int nb) {
  __shared__ int sm[256];
  int v = (threadIdx.x < nb) ? bsum[threadIdx.x] : 0;
  sm[threadIdx.x] = v;
  __syncthreads();
  #pragma unroll
  for (int off = 1; off < 256; off <<= 1) {
    int t = (threadIdx.x >= off) ? sm[threadIdx.x - off] : 0;
    __syncthreads();
    sm[threadIdx.x] += t;
    __syncthreads();
  }
  if (threadIdx.x < nb) bsum[threadIdx.x] = sm[threadIdx.x] - v;
}

__global__ __launch_bounds__(256) void scan3_k(const int* __restrict__ rowtmp,
                                               const int* __restrict__ bsum,
                                               int* __restrict__ rowptr,
                                               int* __restrict__ cursor, int N, int ET) {
  int i = blockIdx.x * 256 + threadIdx.x;
  if (i < N) {
    int v = rowtmp[i] + bsum[blockIdx.x];
    rowptr[i] = v;
    cursor[i] = v;
  }
  if (i == 0) rowptr[N] = ET;
}

__global__ __launch_bounds__(256) void scatter_k(const int* __restrict__ ei, int E, int ET,
                                                 int* __restrict__ cursor,
                                                 int* __restrict__ srcs) {
  int e = blockIdx.x * 256 + threadIdx.x;
  if (e >= ET) return;
  int s, d;
  if (e < E) { s = ei[e]; d = ei[E + e]; } else { s = d = e - E; }
  int pos = atomicAdd(&cursor[d], 1);
  srcs[pos] = s;
}

// ---------------- GEMM1 + alpha1: h1 = X @ W1; as/ad = head-dots ----------------
__global__ __launch_bounds__(256) void gemm1_k(const float* __restrict__ X,
                                               const float* __restrict__ W,
                                               const float* __restrict__ aw_s,
                                               const float* __restrict__ aw_d,
                                               float* __restrict__ Hout,
                                               float* __restrict__ as,
                                               float* __restrict__ ad, int N) {
  __shared__ float wl[32 * 128];   // 16 KB
  __shared__ float xt[32][72];     // ~9 KB, transposed [k][row]
  int cl = threadIdx.x & 31, rg = threadIdx.x >> 5;
  int c4 = cl * 4;
  int n0 = blockIdx.x * 64;
  float acc[8][4] = {};
  const float4* X4 = (const float4*)X;
  const float4* W4 = (const float4*)W;
  for (int k0 = 0; k0 < 128; k0 += 32) {
    __syncthreads();
    for (int i = threadIdx.x; i < 1024; i += 256)
      ((float4*)wl)[i] = W4[k0 * 32 + i];
    for (int i = threadIdx.x; i < 512; i += 256) {
      int r = i >> 3, kk4 = (i & 7) * 4;
      int n = n0 + r;
      float4 xv = (n < N) ? X4[(size_t)n * 32 + (k0 >> 2) + (i & 7)]
                          : make_float4(0.f, 0.f, 0.f, 0.f);
      xt[kk4 + 0][r] = xv.x; xt[kk4 + 1][r] = xv.y;
      xt[kk4 + 2][r] = xv.z; xt[kk4 + 3][r] = xv.w;
    }
    __syncthreads();
    #pragma unroll 8
    for (int kk = 0; kk < 32; ++kk) {
      float4 w4 = *(const float4*)&wl[kk * 128 + c4];
      float4 xa = *(const float4*)&xt[kk][rg * 8];
      float4 xb = *(const float4*)&xt[kk][rg * 8 + 4];
      float xr[8] = {xa.x, xa.y, xa.z, xa.w, xb.x, xb.y, xb.z, xb.w};
      #pragma unroll
      for (int j = 0; j < 8; ++j) {
        acc[j][0] += xr[j] * w4.x; acc[j][1] += xr[j] * w4.y;
        acc[j][2] += xr[j] * w4.z; acc[j][3] += xr[j] * w4.w;
      }
    }
  }
  float4 aws = *(const float4*)&aw_s[c4];
  float4 awd = *(const float4*)&aw_d[c4];
  #pragma unroll
  for (int j = 0; j < 8; ++j) {
    int n = n0 + rg * 8 + j;
    float ps = acc[j][0] * aws.x + acc[j][1] * aws.y + acc[j][2] * aws.z + acc[j][3] * aws.w;
    float pd = acc[j][0] * awd.x + acc[j][1] * awd.y + acc[j][2] * awd.z + acc[j][3] * awd.w;
    ps += __shfl_xor(ps, 1); ps += __shfl_xor(ps, 2); ps += __shfl_xor(ps, 4);
    pd += __shfl_xor(pd, 1); pd += __shfl_xor(pd, 2); pd += __shfl_xor(pd, 4);
    if (n < N) {
      *(float4*)&Hout[(size_t)n * 128 + c4] =
          make_float4(acc[j][0], acc[j][1], acc[j][2], acc[j][3]);
      if ((cl & 7) == 0) {
        as[n * 4 + (cl >> 3)] = ps;
        ad[n * 4 + (cl >> 3)] = pd;
      }
    }
  }
}

// ---------------- GEMM2 + alpha2: h2 = X @ W2 (128->64); as2/ad2 ----------------
__global__ __launch_bounds__(256) void gemm2_k(const float* __restrict__ X,
                                               const float* __restrict__ W,
                                               const float* __restrict__ aw_s,
                                               const float* __restrict__ aw_d,
                                               float* __restrict__ Hout,
                                               float* __restrict__ as,
                                               float* __restrict__ ad, int N) {
  __shared__ float wl[32 * 64];    // 8 KB
  __shared__ float xt[32][72];     // ~9 KB
  int cl = threadIdx.x & 15, rg = threadIdx.x >> 4;
  int c4 = cl * 4;
  int n0 = blockIdx.x * 64;
  float acc[4][4] = {};
  const float4* X4 = (const float4*)X;
  const float4* W4 = (const float4*)W;
  for (int k0 = 0; k0 < 128; k0 += 32) {
    __syncthreads();
    for (int i = threadIdx.x; i < 512; i += 256)
      ((float4*)wl)[i] = W4[k0 * 16 + i];
    for (int i = threadIdx.x; i < 512; i += 256) {
      int r = i >> 3, kk4 = (i & 7) * 4;
      int n = n0 + r;
      float4 xv = (n < N) ? X4[(size_t)n * 32 + (k0 >> 2) + (i & 7)]
                          : make_float4(0.f, 0.f, 0.f, 0.f);
      xt[kk4 + 0][r] = xv.x; xt[kk4 + 1][r] = xv.y;
      xt[kk4 + 2][r] = xv.z; xt[kk4 + 3][r] = xv.w;
    }
    __syncthreads();
    #pragma unroll 8
    for (int kk = 0; kk < 32; ++kk) {
      float4 w4 = *(const float4*)&wl[kk * 64 + c4];
      float4 xa = *(const float4*)&xt[kk][rg * 4];
      float xr[4] = {xa.x, xa.y, xa.z, xa.w};
      #pragma unroll
      for (int j = 0; j < 4; ++j) {
        acc[j][0] += xr[j] * w4.x; acc[j][1] += xr[j] * w4.y;
        acc[j][2] += xr[j] * w4.z; acc[j][3] += xr[j] * w4.w;
      }
    }
  }
  float4 aws = *(const float4*)&aw_s[c4];
  float4 awd = *(const float4*)&aw_d[c4];
  #pragma unroll
  for (int j = 0; j < 4; ++j) {
    int n = n0 + rg * 4 + j;
    float ps = acc[j][0] * aws.x + acc[j][1] * aws.y + acc[j][2] * aws.z + acc[j][3] * aws.w;
    float pd = acc[j][0] * awd.x + acc[j][1] * awd.y + acc[j][2] * awd.z + acc[j][3] * awd.w;
    ps += __shfl_xor(ps, 1); ps += __shfl_xor(ps, 2);
    ps += __shfl_xor(ps, 4); ps += __shfl_xor(ps, 8);
    pd += __shfl_xor(pd, 1); pd += __shfl_xor(pd, 2);
    pd += __shfl_xor(pd, 4); pd += __shfl_xor(pd, 8);
    if (n < N) {
      *(float4*)&Hout[(size_t)n * 64 + c4] =
          make_float4(acc[j][0], acc[j][1], acc[j][2], acc[j][3]);
      if (cl == 0) { as[n] = ps; ad[n] = pd; }
    }
  }
}

// ---------------- layer-1 aggregation ----------------
__global__ __launch_bounds__(256) void agg1_k(const int* __restrict__ rowptr,
                                              const int* __restrict__ srcs,
                                              const float* __restrict__ as,
                                              const float* __restrict__ ad,
                                              const float* __restrict__ Hm,
                                              const float* __restrict__ bias,
                                              float* __restrict__ out, int N) {
  int n = blockIdx.x * 4 + (threadIdx.x >> 6);
  if (n >= N) return;
  int lane = threadIdx.x & 63;
  int grp = lane >> 4;
  int gl  = lane & 15;
  int h   = gl >> 2;
  int r0 = rowptr[n], r1 = rowptr[n + 1];
  int deg = r1 - r0;
  float4 adn = *(const float4*)&ad[n * 4];
  bool small = (deg <= 64);

  float a0 = 0.f, a1 = 0.f, a2 = 0.f, a3 = 0.f,
        a4 = 0.f, a5 = 0.f, a6 = 0.f, a7 = 0.f;
  int cbase = gl * 8;

  if (small) {
    // one edge per lane; all shfls at full exec mask
    int rl = r0 + lane;
    float e0 = -INFINITY, e1 = -INFINITY, e2 = -INFINITY, e3 = -INFINITY;
    if (rl < r1) {
      int s = srcs[rl];
      float4 av = *(const float4*)&as[s * 4];
      e0 = leaky(av.x + adn.x); e1 = leaky(av.y + adn.y);
      e2 = leaky(av.z + adn.z); e3 = leaky(av.w + adn.w);
    }
    float m0 = e0, m1 = e1, m2 = e2, m3 = e3;
    #pragma unroll
    for (int off = 32; off > 0; off >>= 1) {
      m0 = fmaxf(m0, __shfl_xor(m0, off)); m1 = fmaxf(m1, __shfl_xor(m1, off));
      m2 = fmaxf(m2, __shfl_xor(m2, off)); m3 = fmaxf(m3, __shfl_xor(m3, off));
    }
    float sc0 = (rl < r1) ? __expf(e0 - m0) : 0.f;
    float sc1 = (rl < r1) ? __expf(e1 - m1) : 0.f;
    float sc2 = (rl < r1) ? __expf(e2 - m2) : 0.f;
    float sc3 = (rl < r1) ? __expf(e3 - m3) : 0.f;
    float s0 = sc0, s1 = sc1, s2 = sc2, s3 = sc3;
    #pragma unroll
    for (int off = 32; off > 0; off >>= 1) {
      s0 += __shfl_xor(s0, off); s1 += __shfl_xor(s1, off);
      s2 += __shfl_xor(s2, off); s3 += __shfl_xor(s3, off);
    }
    float al0 = sc0 * (1.f / s0), al1 = sc1 * (1.f / s1);
    float al2 = sc2 * (1.f / s2), al3 = sc3 * (1.f / s3);

    // phase B: wave-uniform trip count; shfls unconditional, validity masked
    int iters = (deg + 7) >> 3;
    for (int it = 0; it < iters; ++it) {
      int iA = it * 8 + grp;
      int iB = iA + 4;
      float tA0 = __shfl(al0, iA), tA1 = __shfl(al1, iA),
            tA2 = __shfl(al2, iA), tA3 = __shfl(al3, iA);
      float tB0 = __shfl(al0, iB), tB1 = __shfl(al1, iB),
            tB2 = __shfl(al2, iB), tB3 = __shfl(al3, iB);
      bool vA = iA < deg, vB = iB < deg;
      float alA = vA ? ((h == 0) ? tA0 : (h == 1) ? tA1 : (h == 2) ? tA2 : tA3) : 0.f;
      float alB = vB ? ((h == 0) ? tB0 : (h == 1) ? tB1 : (h == 2) ? tB2 : tB3) : 0.f;
      int sA = srcs[r0 + (vA ? iA : 0)];
      int sB = srcs[r0 + (vB ? iB : 0)];
      const float* rowA = &Hm[(size_t)sA * 128 + cbase];
      const float* rowB = &Hm[(size_t)sB * 128 + cbase];
      float4 hA0 = *(const float4*)rowA, hA1 = *(const float4*)(rowA + 4);
      float4 hB0 = *(const float4*)rowB, hB1 = *(const float4*)(rowB + 4);
      a0 += hA0.x * alA + hB0.x * alB; a1 += hA0.y * alA + hB0.y * alB;
      a2 += hA0.z * alA + hB0.z * alB; a3 += hA0.w * alA + hB0.w * alB;
      a4 += hA1.x * alA + hB1.x * alB; a5 += hA1.y * alA + hB1.y * alB;
      a6 += hA1.z * alA + hB1.z * alB; a7 += hA1.w * alA + hB1.w * alB;
    }
  } else {
    float m0 = -INFINITY, m1 = -INFINITY, m2 = -INFINITY, m3 = -INFINITY;
    for (int r = r0 + lane; r < r1; r += 64) {
      int s = srcs[r];
      float4 av = *(const float4*)&as[s * 4];
      m0 = fmaxf(m0, leaky(av.x + adn.x)); m1 = fmaxf(m1, leaky(av.y + adn.y));
      m2 = fmaxf(m2, leaky(av.z + adn.z)); m3 = fmaxf(m3, leaky(av.w + adn.w));
    }
    #pragma unroll
    for (int off = 32; off > 0; off >>= 1) {
      m0 = fmaxf(m0, __shfl_xor(m0, off)); m1 = fmaxf(m1, __shfl_xor(m1, off));
      m2 = fmaxf(m2, __shfl_xor(m2, off)); m3 = fmaxf(m3, __shfl_xor(m3, off));
    }
    float s0 = 0.f, s1 = 0.f, s2 = 0.f, s3 = 0.f;
    for (int r = r0 + lane; r < r1; r += 64) {
      int s = srcs[r];
      float4 av = *(const float4*)&as[s * 4];
      s0 += __expf(leaky(av.x + adn.x) - m0); s1 += __expf(leaky(av.y + adn.y) - m1);
      s2 += __expf(leaky(av.z + adn.z) - m2); s3 += __expf(leaky(av.w + adn.w) - m3);
    }
    #pragma unroll
    for (int off = 32; off > 0; off >>= 1) {
      s0 += __shfl_xor(s0, off); s1 += __shfl_xor(s1, off);
      s2 += __shfl_xor(s2, off); s3 += __shfl_xor(s3, off);
    }
    float mhh = (h == 0) ? m0 : (h == 1) ? m1 : (h == 2) ? m2 : m3;
    float inv = 1.f / ((h == 0) ? s0 : (h == 1) ? s1 : (h == 2) ? s2 : s3);
    float adh = (h == 0) ? adn.x : (h == 1) ? adn.y : (h == 2) ? adn.z : adn.w;
    // uniform-bound masked loop, no shfl inside
    for (int r = r0; r < r1; r += 8) {
      int rA = r + grp, rB = rA + 4;
      bool vA = rA < r1, vB = rB < r1;
      int sA = srcs[vA ? rA : r0];
      int sB = srcs[vB ? rB : r0];
      float avA = as[sA * 4 + h], avB = as[sB * 4 + h];
      float alA = vA ? (__expf(leaky(avA + adh) - mhh) * inv) : 0.f;
      float alB = vB ? (__expf(leaky(avB + adh) - mhh) * inv) : 0.f;
      const float* rowA = &Hm[(size_t)sA * 128 + cbase];
      const float* rowB = &Hm[(size_t)sB * 128 + cbase];
      float4 hA0 = *(const float4*)rowA, hA1 = *(const float4*)(rowA + 4);
      float4 hB0 = *(const float4*)rowB, hB1 = *(const float4*)(rowB + 4);
      a0 += hA0.x * alA + hB0.x * alB; a1 += hA0.y * alA + hB0.y * alB;
      a2 += hA0.z * alA + hB0.z * alB; a3 += hA0.w * alA + hB0.w * alB;
      a4 += hA1.x * alA + hB1.x * alB; a5 += hA1.y * alA + hB1.y * alB;
      a6 += hA1.z * alA + hB1.z * alB; a7 += hA1.w * alA + hB1.w * alB;
    }
  }
  a0 += __shfl_xor(a0, 16); a0 += __shfl_xor(a0, 32);
  a1 += __shfl_xor(a1, 16); a1 += __shfl_xor(a1, 32);
  a2 += __shfl_xor(a2, 16); a2 += __shfl_xor(a2, 32);
  a3 += __shfl_xor(a3, 16); a3 += __shfl_xor(a3, 32);
  a4 += __shfl_xor(a4, 16); a4 += __shfl_xor(a4, 32);
  a5 += __shfl_xor(a5, 16); a5 += __shfl_xor(a5, 32);
  a6 += __shfl_xor(a6, 16); a6 += __shfl_xor(a6, 32);
  a7 += __shfl_xor(a7, 16); a7 += __shfl_xor(a7, 32);

  if (grp == 0) {
    float4 b0 = *(const float4*)&bias[cbase];
    float4 b1 = *(const float4*)&bias[cbase + 4];
    float4 o0, o1;
    o0.x = fmaxf(a0 + b0.x, 0.f); o0.y = fmaxf(a1 + b0.y, 0.f);
    o0.z = fmaxf(a2 + b0.z, 0.f); o0.w = fmaxf(a3 + b0.w, 0.f);
    o1.x = fmaxf(a4 + b1.x, 0.f); o1.y = fmaxf(a5 + b1.y, 0.f);
    o1.z = fmaxf(a6 + b1.z, 0.f); o1.w = fmaxf(a7 + b1.w, 0.f);
    *(float4*)&out[(size_t)n * 128 + cbase] = o0;
    *(float4*)&out[(size_t)n * 128 + cbase + 4] = o1;
  }
}

// ---------------- layer-2 aggregation (H=1, C=64) ----------------
__global__ __launch_bounds__(256) void agg2_k(const int* __restrict__ rowptr,
                                              const int* __restrict__ srcs,
                                              const float* __restrict__ as,
                                              const float* __restrict__ ad,
                                              const float* __restrict__ Hm,
                                              const float* __restrict__ bias,
                                              float* __restrict__ out, int N) {
  int n = blockIdx.x * 4 + (threadIdx.x >> 6);
  if (n >= N) return;
  int lane = threadIdx.x & 63;
  int grp = lane >> 4;
  int gl  = lane & 15;
  int r0 = rowptr[n], r1 = rowptr[n + 1];
  int deg = r1 - r0;
  float adn = ad[n];
  bool small = (deg <= 64);

  float a0 = 0.f, a1 = 0.f, a2 = 0.f, a3 = 0.f;
  int cbase = gl * 4;

  if (small) {
    int rl = r0 + lane;
    float e = -INFINITY;
    if (rl < r1) e = leaky(as[srcs[rl]] + adn);
    float m = e;
    #pragma unroll
    for (int off = 32; off > 0; off >>= 1) m = fmaxf(m, __shfl_xor(m, off));
    float sc = (rl < r1) ? __expf(e - m) : 0.f;
    float s = sc;
    #pragma unroll
    for (int off = 32; off > 0; off >>= 1) s += __shfl_xor(s, off);
    float alc = sc * (1.f / s);

    int iters = (deg + 7) >> 3;
    for (int it = 0; it < iters; ++it) {
      int iA = it * 8 + grp;
      int iB = iA + 4;
      float tA = __shfl(alc, iA);
      float tB = __shfl(alc, iB);
      bool vA = iA < deg, vB = iB < deg;
      float alA = vA ? tA : 0.f;
      float alB = vB ? tB : 0.f;
      int sA = srcs[r0 + (vA ? iA : 0)];
      int sB = srcs[r0 + (vB ? iB : 0)];
      float4 hA = *(const float4*)&Hm[(size_t)sA * 64 + cbase];
      float4 hB = *(const float4*)&Hm[(size_t)sB * 64 + cbase];
      a0 += hA.x * alA + hB.x * alB; a1 += hA.y * alA + hB.y * alB;
      a2 += hA.z * alA + hB.z * alB; a3 += hA.w * alA + hB.w * alB;
    }
  } else {
    float mh = -INFINITY;
    for (int r = r0 + lane; r < r1; r += 64)
      mh = fmaxf(mh, leaky(as[srcs[r]] + adn));
    #pragma unroll
    for (int off = 32; off > 0; off >>= 1) mh = fmaxf(mh, __shfl_xor(mh, off));
    float s = 0.f;
    for (int r = r0 + lane; r < r1; r += 64)
      s += __expf(leaky(as[srcs[r]] + adn) - mh);
    #pragma unroll
    for (int off = 32; off > 0; off >>= 1) s += __shfl_xor(s, off);
    float inv = 1.f / s;

    for (int r = r0; r < r1; r += 8) {
      int rA = r + grp, rB = rA + 4;
      bool vA = rA < r1, vB = rB < r1;
      int sA = srcs[vA ? rA : r0];
      int sB = srcs[vB ? rB : r0];
      float alA = vA ? (__expf(leaky(as[sA] + adn) - mh) * inv) : 0.f;
      float alB = vB ? (__expf(leaky(as[sB] + adn) - mh) * inv) : 0.f;
      float4 hA = *(const float4*)&Hm[(size_t)sA * 64 + cbase];
      float4 hB = *(const float4*)&Hm[(size_t)sB * 64 + cbase];
      a0 += hA.x * alA + hB.x * alB; a1 += hA.y * alA + hB.y * alB;
      a2 += hA.z * alA + hB.z * alB; a3 += hA.w * alA + hB.w * alB;
    }
  }
  a0 += __shfl_xor(a0, 16); a0 += __shfl_xor(a0, 32);
  a1 += __shfl_xor(a1, 16); a1 += __shfl_xor(a1, 32);
  a2 += __shfl_xor(a2, 16); a2 += __shfl_xor(a2, 32);
  a3 += __shfl_xor(a3, 16); a3 += __shfl_xor(a3, 32);

  if (grp == 0) {
    float4 bv = *(const float4*)&bias[cbase];
    float4 o;
    o.x = a0 + bv.x; o.y = a1 + bv.y; o.z = a2 + bv.z; o.w = a3 + bv.w;
    *(float4*)&out[(size_t)n * 64 + cbase] = o;
  }
}

extern "C" void kernel_launch(void* const* d_in, const int* in_sizes, int n_in,
                              void* d_out, int out_size, void* d_ws, size_t ws_size,
                              hipStream_t stream) {
  const float* x   = (const float*)d_in[0];
  const int*   ei  = (const int*)d_in[1];
  // d_in[2] edge_weight: unused by GATConv (edge_dim unset)
  const float* W1  = (const float*)d_in[3];
  const float* aS1 = (const float*)d_in[4];
  const float* aD1 = (const float*)d_in[5];
  const float* b1  = (const float*)d_in[6];
  const float* W2  = (const float*)d_in[7];
  const float* aS2 = (const float*)d_in[8];
  const float* aD2 = (const float*)d_in[9];
  const float* b2  = (const float*)d_in[10];

  const int N  = in_sizes[0] / 128;
  const int E  = in_sizes[2];
  const int ET = E + N;

  float* ws   = (float*)d_ws;
  float* h1   = ws;                           // N*128 (reused as h2 after layer 1)
  float* out1 = h1   + (size_t)N * 128;       // N*128
  float* as1  = out1 + (size_t)N * 128;       // 4N
  float* ad1  = as1  + (size_t)4 * N;         // 4N
  float* as2  = ad1  + (size_t)4 * N;         // N
  float* ad2  = as2  + (size_t)N;             // N
  int*   cnt    = (int*)(ad2 + (size_t)N);    // N
  int*   rowptr = cnt    + N;                 // N+1
  int*   cursor = rowptr + N + 1;             // N
  int*   rowtmp = cursor + N;                 // N
  int*   bsum   = rowtmp + N;                 // 256
  int*   srcs   = bsum   + 256;               // ET
  float* h2   = h1;                           // alias (h1 dead after agg1)
  float* out  = (float*)d_out;                // N*64

  const int eb  = (ET + 255) / 256;
  const int nb  = (N + 255) / 256;            // scan blocks (nb <= 256 required)
  const int nb4 = (N + 3) / 4;
  const int gb  = (N + 63) / 64;              // gemm blocks

  // ---- CSR build (graph shared by both layers) ----
  hipMemsetAsync(cnt, 0, (size_t)N * sizeof(int), stream);
  hist_k<<<eb, 256, 0, stream>>>(ei, E, ET, cnt);
  scan1_k<<<nb, 256, 0, stream>>>(cnt, rowtmp, bsum, N);
  scan2_k<<<1, 256, 0, stream>>>(bsum, nb);
  scan3_k<<<nb, 256, 0, stream>>>(rowtmp, bsum, rowptr, cursor, N, ET);
  scatter_k<<<eb, 256, 0, stream>>>(ei, E, ET, cursor, srcs);

  // ---- layer 1 ----
  gemm1_k<<<gb, 256, 0, stream>>>(x, W1, aS1, aD1, h1, as1, ad1, N);
  agg1_k<<<nb4, 256, 0, stream>>>(rowptr, srcs, as1, ad1, h1, b1, out1, N);

  // ---- layer 2 ----
  gemm2_k<<<gb, 256, 0, stream>>>(out1, W2, aS2, aD2, h2, as2, ad2, N);
  agg2_k<<<nb4, 256, 0, stream>>>(rowptr, srcs, as2, ad2, h2, b2, out, N);
}